// Round 3
// baseline (590.881 us; speedup 1.0000x reference)
//
#include <hip/hip_runtime.h>
#include <hip/hip_bf16.h>

typedef unsigned short u16;
typedef short s16x8 __attribute__((ext_vector_type(8)));
typedef float f32x4 __attribute__((ext_vector_type(4)));

#define EMB 768
#define NH 12
#define HD 64
#define BB 16
#define SS 1024
#define MTOK (BB*SS)      // 16384
#define NQKV (3*EMB)      // 2304
#define QSZ ((size_t)BB*NH*SS*HD)   // 12,582,912 elements

__device__ __forceinline__ float bf2f(u16 b){
  return __uint_as_float(((unsigned)b) << 16);
}
__device__ __forceinline__ u16 f2bf(float f){
  unsigned u = __float_as_uint(f);
  u += 0x7FFFu + ((u >> 16) & 1u);   // RNE
  return (u16)(u >> 16);
}

// -------- detect input dtype: bf16 data has sane exponents; f32-as-u16 ------
// low halves are uniform garbage (37% hit the extreme-exponent test).
__global__ void detect_f32(const u16* __restrict__ x, int* __restrict__ flag){
  __shared__ int cnt;
  if(threadIdx.x == 0) cnt = 0;
  __syncthreads();
  int c = 0;
  for(int i = threadIdx.x; i < 4096; i += 256){
    u16 wv = x[i];
    int e = (wv >> 7) & 0xFF;
    if(e >= 200 || (e <= 40 && (wv & 0x7FFFu) != 0)) c++;
  }
  atomicAdd(&cnt, c);
  __syncthreads();
  if(threadIdx.x == 0) *flag = (cnt > 100) ? 1 : 0;
}

// ---------------- transpose [R,C] -> [C,R] (dims multiple of 32) -------------
// output always bf16; input dtype per flag
__global__ void transpose_any(const void* __restrict__ in, u16* __restrict__ out,
                              int R, int C, const int* __restrict__ flagp){
  const int isf32 = *flagp;
  __shared__ u16 tile[32][33];
  int bx = blockIdx.x * 32, by = blockIdx.y * 32;
  int tx = threadIdx.x & 31, ty = threadIdx.x >> 5;   // 256 threads: ty 0..7
  if(isf32){
    const float* inf = (const float*)in;
    #pragma unroll
    for(int i = 0; i < 32; i += 8)
      tile[ty + i][tx] = f2bf(inf[(size_t)(by + ty + i) * C + bx + tx]);
  } else {
    const u16* inb = (const u16*)in;
    #pragma unroll
    for(int i = 0; i < 32; i += 8)
      tile[ty + i][tx] = inb[(size_t)(by + ty + i) * C + bx + tx];
  }
  __syncthreads();
  #pragma unroll
  for(int i = 0; i < 32; i += 8)
    out[(size_t)(bx + ty + i) * R + by + tx] = tile[tx][ty + i];
}

// ---------------- 128x128 bf16 MFMA GEMM, K=768 ------------------------------
// A: [M,768] row-major (MODE0: dtype per flag; MODE1: always bf16 internal).
// Bt: [N,768] row-major bf16 (weights pre-transposed into ws).
// MODE 0: qkv epilogue (scatter to Q[B,H,S,D], K[B,H,S,D], V^T[B,H,D,S])
// MODE 1: plain C = A@B + bias -> out [M,768], dtype per flag
template<int MODE>
__global__ __launch_bounds__(256) void gemm_kernel(
    const void* __restrict__ Av, const u16* __restrict__ Bt,
    const void* __restrict__ biasv,
    void* __restrict__ out0, u16* __restrict__ out1, u16* __restrict__ out2,
    const int* __restrict__ flagp){
  const int isf32 = *flagp;
  const int K = 768;
  __shared__ u16 As[128][72];
  __shared__ u16 Bs[128][72];
  int tid = threadIdx.x;
  int m0 = blockIdx.y * 128, n0 = blockIdx.x * 128;
  int w = tid >> 6, lane = tid & 63, quad = lane >> 4, l15 = lane & 15;
  int wm = (w >> 1) * 64, wn = (w & 1) * 64;
  f32x4 acc[4][4] = {};

  for(int k0 = 0; k0 < K; k0 += 64){
    __syncthreads();
    // full 128x64 tiles: 1024 thread-stores of 8 elems (4 iters x 256 threads)
    #pragma unroll
    for(int it = 0; it < 4; ++it){
      int idx = it * 256 + tid;
      int r = idx >> 3, c = (idx & 7) * 8;
      *(uint4*)&Bs[r][c] = *(const uint4*)(Bt + (size_t)(n0 + r) * K + k0 + c);
      if(MODE == 0 && isf32){
        const float* p = (const float*)Av + (size_t)(m0 + r) * K + k0 + c;
        float4 f0 = *(const float4*)p;
        float4 f1 = *(const float4*)(p + 4);
        s16x8 t;
        t[0] = (short)f2bf(f0.x); t[1] = (short)f2bf(f0.y);
        t[2] = (short)f2bf(f0.z); t[3] = (short)f2bf(f0.w);
        t[4] = (short)f2bf(f1.x); t[5] = (short)f2bf(f1.y);
        t[6] = (short)f2bf(f1.z); t[7] = (short)f2bf(f1.w);
        *(s16x8*)&As[r][c] = t;
      } else {
        *(uint4*)&As[r][c] =
            *(const uint4*)((const u16*)Av + (size_t)(m0 + r) * K + k0 + c);
      }
    }
    __syncthreads();
    #pragma unroll
    for(int kk = 0; kk < 64; kk += 32){
      s16x8 a[4], b[4];
      #pragma unroll
      for(int i = 0; i < 4; i++){
        a[i] = *(const s16x8*)&As[wm + i*16 + l15][kk + quad*8];
        b[i] = *(const s16x8*)&Bs[wn + i*16 + l15][kk + quad*8];
      }
      #pragma unroll
      for(int mt = 0; mt < 4; mt++)
        #pragma unroll
        for(int nt = 0; nt < 4; nt++)
          acc[mt][nt] = __builtin_amdgcn_mfma_f32_16x16x32_bf16(
                            a[mt], b[nt], acc[mt][nt], 0, 0, 0);
    }
  }

  #pragma unroll
  for(int mt = 0; mt < 4; mt++){
    #pragma unroll
    for(int nt = 0; nt < 4; nt++){
      int n = n0 + wn + nt*16 + l15;
      float bv = isf32 ? ((const float*)biasv)[n] : bf2f(((const u16*)biasv)[n]);
      #pragma unroll
      for(int r = 0; r < 4; r++){
        int m = m0 + wm + mt*16 + quad*4 + r;
        float v = acc[mt][nt][r] + bv;
        if(MODE == 1){
          if(isf32) ((float*)out0)[(size_t)m * EMB + n] = v;
          else      ((u16*)out0)[(size_t)m * EMB + n] = f2bf(v);
        } else {
          u16 hv = f2bf(v);
          int which = n / EMB, rem = n - which * EMB;
          int h = rem >> 6, d = rem & 63;
          int b = m >> 10, s = m & 1023;
          size_t bh = (size_t)(b * NH + h);
          if(which == 0)      ((u16*)out0)[(bh * SS + s) * HD + d] = hv;  // Q
          else if(which == 1) out1[(bh * SS + s) * HD + d] = hv;          // K
          else                out2[(bh * HD + d) * SS + s] = hv;          // V^T
        }
      }
    }
  }
}

// ---------------- flash attention: block = (b, h, 64 q-rows) -----------------
__global__ __launch_bounds__(256) void attn_kernel(
    const u16* __restrict__ Qws, const u16* __restrict__ Kws,
    const u16* __restrict__ Vtws, u16* __restrict__ attn){
  __shared__ u16 Ks[128][72];      // keys, d-contiguous
  __shared__ u16 Vs[64][136];      // V^T: rows d, s-contiguous
  __shared__ u16 Ps[4][16][136];   // per-wave P (A-layout target)
  int tid = threadIdx.x;
  int w = tid >> 6, lane = tid & 63, quad = lane >> 4, l15 = lane & 15;
  int q0 = blockIdx.x * 64;
  int h = blockIdx.y, b = blockIdx.z;
  size_t bh = (size_t)(b * NH + h);
  const u16* Qbase = Qws  + bh * SS * HD;
  const u16* Kbase = Kws  + bh * SS * HD;
  const u16* Vbase = Vtws + bh * HD * SS;

  // Q fragments (A-layout): row = q0 + w*16 + l15, k = kk*32 + quad*8 + j
  s16x8 aq[2];
  int qrow = q0 + w*16 + l15;
  #pragma unroll
  for(int kk = 0; kk < 2; kk++)
    aq[kk] = *(const s16x8*)(Qbase + (size_t)qrow * HD + kk*32 + quad*8);

  float mi[4], li[4];
  f32x4 o[4] = {};
  #pragma unroll
  for(int r = 0; r < 4; r++){ mi[r] = -1e30f; li[r] = 0.f; }

  for(int kt = 0; kt < 8; ++kt){
    __syncthreads();
    // K tile: 128 rows x 64 d -> 1024 thread-loads of 8 (4 iters)
    #pragma unroll
    for(int it = 0; it < 4; ++it){
      int idx = it * 256 + tid;
      int r = idx >> 3, c = (idx & 7) * 8;
      *(uint4*)&Ks[r][c] = *(const uint4*)(Kbase + (size_t)(kt*128 + r) * HD + c);
    }
    // V^T tile: 64 rows x 128 s -> 1024 thread-loads of 8 (4 iters)
    #pragma unroll
    for(int it = 0; it < 4; ++it){
      int idx = it * 256 + tid;
      int r = idx >> 4, c = (idx & 15) * 8;
      *(uint4*)&Vs[r][c] = *(const uint4*)(Vbase + (size_t)r * SS + kt*128 + c);
    }
    __syncthreads();

    // scores: 16 q-rows x 128 keys
    f32x4 sc[8];
    #pragma unroll
    for(int nt = 0; nt < 8; nt++){
      f32x4 z = {};
      #pragma unroll
      for(int kk = 0; kk < 2; kk++){
        s16x8 bk = *(const s16x8*)&Ks[nt*16 + l15][kk*32 + quad*8];
        z = __builtin_amdgcn_mfma_f32_16x16x32_bf16(aq[kk], bk, z, 0, 0, 0);
      }
      sc[nt] = z * 0.125f;   // 1/sqrt(64)
    }

    // online softmax (row = quad*4 + r; masks 1..8 stay inside the 16-lane quad)
    float alpha[4];
    #pragma unroll
    for(int r = 0; r < 4; r++){
      float mx = sc[0][r];
      #pragma unroll
      for(int nt = 1; nt < 8; nt++) mx = fmaxf(mx, sc[nt][r]);
      #pragma unroll
      for(int msk = 1; msk < 16; msk <<= 1) mx = fmaxf(mx, __shfl_xor(mx, msk, 64));
      float mn = fmaxf(mi[r], mx);
      alpha[r] = __expf(mi[r] - mn);
      float s = 0.f;
      #pragma unroll
      for(int nt = 0; nt < 8; nt++){
        float p = __expf(sc[nt][r] - mn);
        sc[nt][r] = p;
        s += p;
      }
      #pragma unroll
      for(int msk = 1; msk < 16; msk <<= 1) s += __shfl_xor(s, msk, 64);
      li[r] = li[r] * alpha[r] + s;
      mi[r] = mn;
    }
    #pragma unroll
    for(int nt = 0; nt < 4; nt++)
      #pragma unroll
      for(int r = 0; r < 4; r++) o[nt][r] *= alpha[r];

    // P: C-layout -> LDS -> A-layout
    #pragma unroll
    for(int nt = 0; nt < 8; nt++)
      #pragma unroll
      for(int r = 0; r < 4; r++)
        Ps[w][quad*4 + r][nt*16 + l15] = f2bf(sc[nt][r]);
    __syncthreads();

    // PV: o(16x64) += P(16x128) @ V(128x64)
    #pragma unroll
    for(int k4 = 0; k4 < 4; k4++){
      s16x8 pa = *(const s16x8*)&Ps[w][l15][k4*32 + quad*8];
      #pragma unroll
      for(int nt = 0; nt < 4; nt++){
        s16x8 vb = *(const s16x8*)&Vs[nt*16 + l15][k4*32 + quad*8];
        o[nt] = __builtin_amdgcn_mfma_f32_16x16x32_bf16(pa, vb, o[nt], 0, 0, 0);
      }
    }
  }

  // epilogue: attn[b, s, h*64+d]  (always internal bf16)
  #pragma unroll
  for(int r = 0; r < 4; r++){
    float inv = 1.f / li[r];
    int srow = q0 + w*16 + quad*4 + r;
    size_t base = ((size_t)(b * SS + srow)) * EMB + h * HD;
    #pragma unroll
    for(int nt = 0; nt < 4; nt++)
      attn[base + nt*16 + l15] = f2bf(o[nt][r] * inv);
  }
}

extern "C" void kernel_launch(void* const* d_in, const int* in_sizes, int n_in,
                              void* d_out, int out_size, void* d_ws, size_t ws_size,
                              hipStream_t stream){
  const void* x      = d_in[0];
  const void* qkv_w  = d_in[1];
  const void* qkv_b  = d_in[2];
  const void* proj_w = d_in[3];
  const void* proj_b = d_in[4];

  char* ws = (char*)d_ws;
  int* flag = (int*)ws;    ws += 16;
  u16* qkv_wT  = (u16*)ws; ws += (size_t)NQKV * EMB * 2;   // [2304,768]
  u16* proj_wT = (u16*)ws; ws += (size_t)EMB * EMB * 2;    // [768,768]
  u16* Qws  = (u16*)ws; ws += QSZ * 2;                     // [B,H,S,D]
  u16* Kws  = (u16*)ws; ws += QSZ * 2;                     // [B,H,S,D]
  u16* Vtws = (u16*)ws; ws += QSZ * 2;                     // [B,H,D,S]
  u16* attn = (u16*)ws; ws += QSZ * 2;                     // [B*S, 768] bf16

  detect_f32<<<1, 256, 0, stream>>>((const u16*)x, flag);
  transpose_any<<<dim3(NQKV/32, EMB/32), 256, 0, stream>>>(qkv_w, qkv_wT, EMB, NQKV, flag);
  transpose_any<<<dim3(EMB/32, EMB/32), 256, 0, stream>>>(proj_w, proj_wT, EMB, EMB, flag);
  gemm_kernel<0><<<dim3(NQKV/128, MTOK/128), 256, 0, stream>>>(
      x, qkv_wT, qkv_b, Qws, Kws, Vtws, flag);
  attn_kernel<<<dim3(SS/64, NH, BB), 256, 0, stream>>>(Qws, Kws, Vtws, attn);
  gemm_kernel<1><<<dim3(EMB/128, MTOK/128), 256, 0, stream>>>(
      attn, proj_wT, proj_b, d_out, nullptr, nullptr, flag);
}

// Round 4
// 444.017 us; speedup vs baseline: 1.3308x; 1.3308x over previous
//
#include <hip/hip_runtime.h>
#include <hip/hip_bf16.h>

typedef unsigned short u16;
typedef short s16x8 __attribute__((ext_vector_type(8)));
typedef float f32x4 __attribute__((ext_vector_type(4)));

#define EMB 768
#define NH 12
#define HD 64
#define BB 16
#define SS 1024
#define MTOK (BB*SS)      // 16384
#define NQKV (3*EMB)      // 2304
#define QSZ ((size_t)BB*NH*SS*HD)   // 12,582,912 elements

#define GLOBAL_AS const __attribute__((address_space(1))) void*
#define LDS_AS __attribute__((address_space(3))) void*

__device__ __forceinline__ u16 f2bf(float f){
  unsigned u = __float_as_uint(f);
  u += 0x7FFFu + ((u >> 16) & 1u);   // RNE
  return (u16)(u >> 16);
}

// ---------------- x: f32 -> bf16 bulk convert --------------------------------
__global__ __launch_bounds__(256) void convert_f32_bf16(
    const float4* __restrict__ in, ushort4* __restrict__ out, int n4){
  int i = blockIdx.x * 256 + threadIdx.x;
  if(i < n4){
    float4 f = in[i];
    ushort4 o;
    o.x = f2bf(f.x); o.y = f2bf(f.y); o.z = f2bf(f.z); o.w = f2bf(f.w);
    out[i] = o;
  }
}

// ---------------- transpose+convert [R,C] f32 -> [C,R] bf16 ------------------
__global__ void transpose_conv(const float* __restrict__ in, u16* __restrict__ out,
                               int R, int C){
  __shared__ u16 tile[32][33];
  int bx = blockIdx.x * 32, by = blockIdx.y * 32;
  int tx = threadIdx.x & 31, ty = threadIdx.x >> 5;   // 256 threads: ty 0..7
  #pragma unroll
  for(int i = 0; i < 32; i += 8)
    tile[ty + i][tx] = f2bf(in[(size_t)(by + ty + i) * C + bx + tx]);
  __syncthreads();
  #pragma unroll
  for(int i = 0; i < 32; i += 8)
    out[(size_t)(bx + ty + i) * R + by + tx] = tile[tx][ty + i];
}

// ---------------- 128x128 bf16 MFMA GEMM, K=768 ------------------------------
// A: [M,768] bf16 row-major. Bt: [N,768] bf16 row-major (weights pre-transposed).
// Staging: global_load_lds width=16, XOR-swizzled [128][64] LDS tiles:
//   LDS 16B-chunk position (r, cp) holds global chunk cp ^ (r&7) of row r.
// MODE 0: qkv epilogue (scatter Q[B,H,S,D], K[B,H,S,D], V^T[B,H,D,S], bf16)
// MODE 1: C = A@B + bias -> out0 [M,768] f32
template<int MODE>
__global__ __launch_bounds__(256) void gemm_kernel(
    const u16* __restrict__ A, const u16* __restrict__ Bt,
    const float* __restrict__ bias,
    void* __restrict__ out0, u16* __restrict__ out1, u16* __restrict__ out2){
  const int K = 768;
  __shared__ u16 As[128*64];
  __shared__ u16 Bs[128*64];
  int tid = threadIdx.x;
  int m0 = blockIdx.y * 128, n0 = blockIdx.x * 128;
  int w = tid >> 6, lane = tid & 63, quad = lane >> 4, l15 = lane & 15;
  int wm = (w >> 1) * 64, wn = (w & 1) * 64;
  int rr = lane >> 3;          // row within a 1KB chunk-issue (0..7)
  int cp = lane & 7;           // 16B chunk position within row
  f32x4 acc[4][4] = {};

  for(int k0 = 0; k0 < K; k0 += 64){
    __syncthreads();
    #pragma unroll
    for(int it = 0; it < 4; ++it){
      int ci = it * 4 + w;             // 0..15: which 1KB slice of the 16KB tile
      int r  = ci * 8 + rr;            // tile row this lane stages
      int gc = (cp ^ (r & 7)) * 8;     // swizzled source column (elements)
      __builtin_amdgcn_global_load_lds(
          (GLOBAL_AS)(A + (size_t)(m0 + r) * K + k0 + gc),
          (LDS_AS)(As + ci * 512 + lane * 8), 16, 0, 0);
      __builtin_amdgcn_global_load_lds(
          (GLOBAL_AS)(Bt + (size_t)(n0 + r) * K + k0 + gc),
          (LDS_AS)(Bs + ci * 512 + lane * 8), 16, 0, 0);
    }
    __syncthreads();
    #pragma unroll
    for(int kk = 0; kk < 2; kk++){
      s16x8 a[4], b[4];
      int ch = ((kk * 4 + quad) ^ (l15 & 7)) * 8;   // swizzled chunk offset
      #pragma unroll
      for(int i = 0; i < 4; i++){
        a[i] = *(const s16x8*)&As[(wm + i*16 + l15) * 64 + ch];
        b[i] = *(const s16x8*)&Bs[(wn + i*16 + l15) * 64 + ch];
      }
      #pragma unroll
      for(int mt = 0; mt < 4; mt++)
        #pragma unroll
        for(int nt = 0; nt < 4; nt++)
          acc[mt][nt] = __builtin_amdgcn_mfma_f32_16x16x32_bf16(
                            a[mt], b[nt], acc[mt][nt], 0, 0, 0);
    }
  }

  #pragma unroll
  for(int mt = 0; mt < 4; mt++){
    #pragma unroll
    for(int nt = 0; nt < 4; nt++){
      int n = n0 + wn + nt*16 + l15;
      float bv = bias[n];
      #pragma unroll
      for(int r = 0; r < 4; r++){
        int m = m0 + wm + mt*16 + quad*4 + r;
        float v = acc[mt][nt][r] + bv;
        if(MODE == 1){
          ((float*)out0)[(size_t)m * EMB + n] = v;
        } else {
          u16 hv = f2bf(v);
          int which = n / EMB, rem = n - which * EMB;
          int h = rem >> 6, d = rem & 63;
          int b = m >> 10, s = m & 1023;
          size_t bh = (size_t)(b * NH + h);
          if(which == 0)      ((u16*)out0)[(bh * SS + s) * HD + d] = hv;  // Q
          else if(which == 1) out1[(bh * SS + s) * HD + d] = hv;          // K
          else                out2[(bh * HD + d) * SS + s] = hv;          // V^T
        }
      }
    }
  }
}

// ---------------- flash attention: block = (b, h, 64 q-rows) -----------------
// (unchanged from round 3 — verified correct; optimize next round with profile)
__global__ __launch_bounds__(256) void attn_kernel(
    const u16* __restrict__ Qws, const u16* __restrict__ Kws,
    const u16* __restrict__ Vtws, u16* __restrict__ attn){
  __shared__ u16 Ks[128][72];      // keys, d-contiguous
  __shared__ u16 Vs[64][136];      // V^T: rows d, s-contiguous
  __shared__ u16 Ps[4][16][136];   // per-wave P (A-layout target)
  int tid = threadIdx.x;
  int w = tid >> 6, lane = tid & 63, quad = lane >> 4, l15 = lane & 15;
  int q0 = blockIdx.x * 64;
  int h = blockIdx.y, b = blockIdx.z;
  size_t bh = (size_t)(b * NH + h);
  const u16* Qbase = Qws  + bh * SS * HD;
  const u16* Kbase = Kws  + bh * SS * HD;
  const u16* Vbase = Vtws + bh * HD * SS;

  s16x8 aq[2];
  int qrow = q0 + w*16 + l15;
  #pragma unroll
  for(int kk = 0; kk < 2; kk++)
    aq[kk] = *(const s16x8*)(Qbase + (size_t)qrow * HD + kk*32 + quad*8);

  float mi[4], li[4];
  f32x4 o[4] = {};
  #pragma unroll
  for(int r = 0; r < 4; r++){ mi[r] = -1e30f; li[r] = 0.f; }

  for(int kt = 0; kt < 8; ++kt){
    __syncthreads();
    #pragma unroll
    for(int it = 0; it < 4; ++it){
      int idx = it * 256 + tid;
      int r = idx >> 3, c = (idx & 7) * 8;
      *(uint4*)&Ks[r][c] = *(const uint4*)(Kbase + (size_t)(kt*128 + r) * HD + c);
    }
    #pragma unroll
    for(int it = 0; it < 4; ++it){
      int idx = it * 256 + tid;
      int r = idx >> 4, c = (idx & 15) * 8;
      *(uint4*)&Vs[r][c] = *(const uint4*)(Vbase + (size_t)r * SS + kt*128 + c);
    }
    __syncthreads();

    f32x4 sc[8];
    #pragma unroll
    for(int nt = 0; nt < 8; nt++){
      f32x4 z = {};
      #pragma unroll
      for(int kk = 0; kk < 2; kk++){
        s16x8 bk = *(const s16x8*)&Ks[nt*16 + l15][kk*32 + quad*8];
        z = __builtin_amdgcn_mfma_f32_16x16x32_bf16(aq[kk], bk, z, 0, 0, 0);
      }
      sc[nt] = z * 0.125f;   // 1/sqrt(64)
    }

    float alpha[4];
    #pragma unroll
    for(int r = 0; r < 4; r++){
      float mx = sc[0][r];
      #pragma unroll
      for(int nt = 1; nt < 8; nt++) mx = fmaxf(mx, sc[nt][r]);
      #pragma unroll
      for(int msk = 1; msk < 16; msk <<= 1) mx = fmaxf(mx, __shfl_xor(mx, msk, 64));
      float mn = fmaxf(mi[r], mx);
      alpha[r] = __expf(mi[r] - mn);
      float s = 0.f;
      #pragma unroll
      for(int nt = 0; nt < 8; nt++){
        float p = __expf(sc[nt][r] - mn);
        sc[nt][r] = p;
        s += p;
      }
      #pragma unroll
      for(int msk = 1; msk < 16; msk <<= 1) s += __shfl_xor(s, msk, 64);
      li[r] = li[r] * alpha[r] + s;
      mi[r] = mn;
    }
    #pragma unroll
    for(int nt = 0; nt < 4; nt++)
      #pragma unroll
      for(int r = 0; r < 4; r++) o[nt][r] *= alpha[r];

    #pragma unroll
    for(int nt = 0; nt < 8; nt++)
      #pragma unroll
      for(int r = 0; r < 4; r++)
        Ps[w][quad*4 + r][nt*16 + l15] = f2bf(sc[nt][r]);
    __syncthreads();

    #pragma unroll
    for(int k4 = 0; k4 < 4; k4++){
      s16x8 pa = *(const s16x8*)&Ps[w][l15][k4*32 + quad*8];
      #pragma unroll
      for(int nt = 0; nt < 4; nt++){
        s16x8 vb = *(const s16x8*)&Vs[nt*16 + l15][k4*32 + quad*8];
        o[nt] = __builtin_amdgcn_mfma_f32_16x16x32_bf16(pa, vb, o[nt], 0, 0, 0);
      }
    }
  }

  #pragma unroll
  for(int r = 0; r < 4; r++){
    float inv = 1.f / li[r];
    int srow = q0 + w*16 + quad*4 + r;
    size_t base = ((size_t)(b * SS + srow)) * EMB + h * HD;
    #pragma unroll
    for(int nt = 0; nt < 4; nt++)
      attn[base + nt*16 + l15] = f2bf(o[nt][r] * inv);
  }
}

extern "C" void kernel_launch(void* const* d_in, const int* in_sizes, int n_in,
                              void* d_out, int out_size, void* d_ws, size_t ws_size,
                              hipStream_t stream){
  const float* x      = (const float*)d_in[0];
  const float* qkv_w  = (const float*)d_in[1];
  const float* qkv_b  = (const float*)d_in[2];
  const float* proj_w = (const float*)d_in[3];
  const float* proj_b = (const float*)d_in[4];

  char* ws = (char*)d_ws;
  u16* qkv_wT  = (u16*)ws; ws += (size_t)NQKV * EMB * 2;   // [2304,768] bf16
  u16* proj_wT = (u16*)ws; ws += (size_t)EMB * EMB * 2;    // [768,768] bf16
  u16* x_bf = (u16*)ws; ws += QSZ * 2;   // [16384,768] bf16 (later reused as attn)
  u16* Qws  = (u16*)ws; ws += QSZ * 2;                     // [B,H,S,D]
  u16* Kws  = (u16*)ws; ws += QSZ * 2;                     // [B,H,S,D]
  u16* Vtws = (u16*)ws; ws += QSZ * 2;                     // [B,H,D,S]
  u16* attn = x_bf;   // x_bf dead after QKV GEMM; alias saves 25 MB

  int n4 = (int)(QSZ / 4);
  convert_f32_bf16<<<(n4 + 255) / 256, 256, 0, stream>>>(
      (const float4*)x, (ushort4*)x_bf, n4);
  transpose_conv<<<dim3(NQKV/32, EMB/32), 256, 0, stream>>>(qkv_w, qkv_wT, EMB, NQKV);
  transpose_conv<<<dim3(EMB/32, EMB/32), 256, 0, stream>>>(proj_w, proj_wT, EMB, EMB);
  gemm_kernel<0><<<dim3(NQKV/128, MTOK/128), 256, 0, stream>>>(
      x_bf, qkv_wT, qkv_b, Qws, Kws, Vtws);
  attn_kernel<<<dim3(SS/64, NH, BB), 256, 0, stream>>>(Qws, Kws, Vtws, attn);
  gemm_kernel<1><<<dim3(EMB/128, MTOK/128), 256, 0, stream>>>(
      attn, proj_wT, proj_b, d_out, nullptr, nullptr);
}